// Round 11
// baseline (82.644 us; speedup 1.0000x reference)
//
#include <hip/hip_runtime.h>
#include <hip/hip_bf16.h>
#include <math.h>

#define B_PAIRS 2048
#define N_ROWS  4096
#define D_DIM   256
#define INV_T   2.0f

typedef __attribute__((ext_vector_type(4))) float  floatx4;

// ---- workspace layout ----
// [0, 1MB)   : zn8t — fp8 e4m3, K-BLOCKED: segment s holds k=[32s,32s+32) for
//              all rows: byte addr = s*131072 + row*32 + (k&31).
// [1MB,+16KB): S[4096] (fp32, sum_{j!=i} exp(sim_ij))
// then       : posSum (fp32), cnt (u32)

__device__ __forceinline__ void async_copy16(const void* gsrc, void* ldst) {
    __builtin_amdgcn_global_load_lds(
        (__attribute__((address_space(1))) void*)gsrc,
        (__attribute__((address_space(3))) void*)ldst,
        16, 0, 0);
}

// ---------- kernel 1: row-normalize fp32 -> fp8 e4m3, K-blocked store -------
// Also zero-inits S[row], posSum, cnt.
__global__ __launch_bounds__(256)
void ntx_normalize(const float* __restrict__ z_i,
                   const float* __restrict__ z_j,
                   unsigned* __restrict__ zn8t,  // dword view of K-blocked buf
                   float* __restrict__ S,
                   float* __restrict__ posSum,
                   unsigned* __restrict__ cnt) {
    const int w    = threadIdx.x >> 6;               // wave 0..3
    const int lane = threadIdx.x & 63;
    const int row  = blockIdx.x * 4 + w;             // 0..4095
    const float* src = (row < B_PAIRS) ? (z_i + (size_t)row * D_DIM)
                                       : (z_j + (size_t)(row - B_PAIRS) * D_DIM);
    const float4 v = *(const float4*)(src + lane * 4);   // k = lane*4 .. +3
    float ss = v.x * v.x + v.y * v.y + v.z * v.z + v.w * v.w;
    #pragma unroll
    for (int off = 32; off > 0; off >>= 1) ss += __shfl_xor(ss, off, 64);
    const float rn = 1.0f / fmaxf(sqrtf(ss), 1e-8f);
    unsigned pk = 0;
    pk = __builtin_amdgcn_cvt_pk_fp8_f32(v.x * rn, v.y * rn, pk, false);
    pk = __builtin_amdgcn_cvt_pk_fp8_f32(v.z * rn, v.w * rn, pk, true);
    // k = lane*4 -> segment s = lane>>3, dword-in-seg = row*8 + (lane&7)
    zn8t[(size_t)(lane >> 3) * 32768 + row * 8 + (lane & 7)] = pk;
    if (lane == 0) S[row] = 0.0f;
    if (blockIdx.x == 0 && threadIdx.x == 0) { *posSum = 0.0f; *cnt = 0u; }
}

// ---------- kernel 2: upper-triangle sim tiles, single drain + fused final --
#define BM 128
#define BN 128
#define N_TILES 528            // 32 diag + 496 strictly-upper (32x32 tile grid)

__global__ __launch_bounds__(256)
void ntx_simtile(const unsigned char* __restrict__ zn8t,
                 float* __restrict__ S,
                 float* __restrict__ posSum,
                 unsigned* __restrict__ cnt,
                 float* __restrict__ out) {
    __shared__ __align__(16) unsigned char As[8 * 128 * 32];   // 32 KB
    __shared__ __align__(16) unsigned char Bs[8 * 128 * 32];   // 32 KB

    // linear block id -> upper-triangle (by, bx), bx >= by
    int t = blockIdx.x, by = 0, rowlen = 32;
    while (t >= rowlen) { t -= rowlen; by++; rowlen--; }
    const int bx = by + t;

    const int tid  = threadIdx.x;
    const int lane = tid & 63;
    const int w    = tid >> 6;           // wave 0..3
    const int wr   = w >> 1;             // wave row strip (0..1)
    const int wc   = w & 1;              // wave col strip (0..1)
    const int quad = lane >> 4;          // 0..3
    const int l16  = lane & 15;

    const int rowA0 = by * BM;
    const int rowB0 = bx * BN;
    const bool isDiag = (by == bx);
    const bool isPos  = (rowB0 == (rowA0 ^ B_PAIRS));

    // Stage ALL 8 K-segments for A and B: 16 linear 16-B copies per thread.
    #pragma unroll
    for (int s = 0; s < 8; s++) {
        async_copy16(zn8t + (size_t)s * 131072 + rowA0 * 32 + tid * 16,
                     As + s * 4096 + tid * 16);
        async_copy16(zn8t + (size_t)s * 131072 + rowB0 * 32 + tid * 16,
                     Bs + s * 4096 + tid * 16);
    }
    __syncthreads();   // the ONLY staging drain

    floatx4 acc[4][4];
    #pragma unroll
    for (int i = 0; i < 4; i++)
        #pragma unroll
        for (int j = 0; j < 4; j++)
            acc[i][j] = (floatx4){0.f, 0.f, 0.f, 0.f};

    #pragma unroll
    for (int s = 0; s < 8; s++) {        // K-steps, no barriers
        long afr[4], bfr[4];
        #pragma unroll
        for (int fi = 0; fi < 4; fi++) {
            const int ar = wr * 64 + fi * 16 + l16;
            afr[fi] = *(const long*)(const void*)(As + s * 4096 + ar * 32 + quad * 8);
        }
        #pragma unroll
        for (int fj = 0; fj < 4; fj++) {
            const int br = wc * 64 + fj * 16 + l16;
            bfr[fj] = *(const long*)(const void*)(Bs + s * 4096 + br * 32 + quad * 8);
        }
        #pragma unroll
        for (int fi = 0; fi < 4; fi++)
            #pragma unroll
            for (int fj = 0; fj < 4; fj++)
                acc[fi][fj] = __builtin_amdgcn_mfma_f32_16x16x32_fp8_fp8(
                    afr[fi], bfr[fj], acc[fi][fj], 0, 0, 0);
    }

    // Epilogue. C/D layout: col=l16, row=quad*4+reg.
    float cs[4] = {0.f, 0.f, 0.f, 0.f};
    float psum = 0.f;
    #pragma unroll
    for (int fi = 0; fi < 4; fi++) {
        float rs[4] = {0.f, 0.f, 0.f, 0.f};
        #pragma unroll
        for (int fj = 0; fj < 4; fj++) {
            const int rj = wc * 64 + fj * 16 + l16;
            #pragma unroll
            for (int reg = 0; reg < 4; reg++) {
                const int ri = wr * 64 + fi * 16 + quad * 4 + reg;
                const float v = acc[fi][fj][reg] * INV_T;
                const bool d = (ri == rj);
                if (isPos && d) psum += 2.0f * v;
                const float e = (isDiag && d) ? 0.f : __expf(v);
                rs[reg] += e;
                cs[fj]  += e;
            }
        }
        #pragma unroll
        for (int reg = 0; reg < 4; reg++) {
            float r = rs[reg];
            r += __shfl_xor(r, 1, 16);
            r += __shfl_xor(r, 2, 16);
            r += __shfl_xor(r, 4, 16);
            r += __shfl_xor(r, 8, 16);
            if (l16 == 0)
                atomicAdd(&S[rowA0 + wr * 64 + fi * 16 + quad * 4 + reg], r);
        }
    }
    if (!isDiag) {
        #pragma unroll
        for (int fj = 0; fj < 4; fj++) {
            float c = cs[fj];
            c += __shfl_xor(c, 16, 64);
            c += __shfl_xor(c, 32, 64);
            if (quad == 0)
                atomicAdd(&S[rowB0 + wc * 64 + fj * 16 + l16], c);
        }
    }
    if (isPos) {
        psum += __shfl_xor(psum, 1, 64);  psum += __shfl_xor(psum, 2, 64);
        psum += __shfl_xor(psum, 4, 64);  psum += __shfl_xor(psum, 8, 64);
        psum += __shfl_xor(psum, 16, 64); psum += __shfl_xor(psum, 32, 64);
        __shared__ float pred[4];
        if (lane == 0) pred[w] = psum;
        __syncthreads();
        if (tid == 0)
            atomicAdd(posSum, pred[0] + pred[1] + pred[2] + pred[3]);
    }

    // ---- fused finalize, RELAXED counter (round-4 lesson: no ACQ_REL) ----
    // __syncthreads drains vmcnt(0) for all threads => this block's S/posSum
    // device-scope atomics have completed at the coherence point BEFORE the
    // relaxed counter bump issues. No cache-maintenance ops emitted.
    __shared__ bool amLast;
    __syncthreads();
    if (tid == 0) {
        unsigned old = __hip_atomic_fetch_add(cnt, 1u, __ATOMIC_RELAXED,
                                              __HIP_MEMORY_SCOPE_AGENT);
        amLast = (old == N_TILES - 1);
    }
    __syncthreads();
    if (amLast) {
        float acc2 = 0.f;
        for (int i = tid; i < N_ROWS; i += 256) {
            float sv = __hip_atomic_load(&S[i], __ATOMIC_RELAXED,
                                         __HIP_MEMORY_SCOPE_AGENT);
            acc2 += __logf(sv);
        }
        #pragma unroll
        for (int off = 32; off > 0; off >>= 1) acc2 += __shfl_xor(acc2, off, 64);
        __shared__ float red[4];
        if (lane == 0) red[w] = acc2;
        __syncthreads();
        if (tid == 0) {
            float logsum = red[0] + red[1] + red[2] + red[3];
            float ps = __hip_atomic_load(posSum, __ATOMIC_RELAXED,
                                         __HIP_MEMORY_SCOPE_AGENT);
            out[0] = (logsum - ps) / (float)N_ROWS;
        }
    }
}

extern "C" void kernel_launch(void* const* d_in, const int* in_sizes, int n_in,
                              void* d_out, int out_size, void* d_ws, size_t ws_size,
                              hipStream_t stream) {
    const float* z_i = (const float*)d_in[0];
    const float* z_j = (const float*)d_in[1];
    float* out = (float*)d_out;

    unsigned char* zn8t = (unsigned char*)d_ws;
    float* S      = (float*)((char*)d_ws + (size_t)N_ROWS * D_DIM);  // 1 MB
    float* posSum = S + N_ROWS;
    unsigned* cnt = (unsigned*)(posSum + 1);

    ntx_normalize<<<N_ROWS / 4, 256, 0, stream>>>(z_i, z_j, (unsigned*)zn8t,
                                                  S, posSum, cnt);
    ntx_simtile<<<N_TILES, 256, 0, stream>>>(zn8t, S, posSum, cnt, out);
}

// Round 12
// 77.160 us; speedup vs baseline: 1.0711x; 1.0711x over previous
//
#include <hip/hip_runtime.h>
#include <hip/hip_bf16.h>
#include <math.h>

#define B_PAIRS 2048
#define N_ROWS  4096
#define D_DIM   256
#define INV_T   2.0f

typedef __attribute__((ext_vector_type(4))) float  floatx4;

// ---- workspace layout ----
// [0, 1MB)   : zn8t — fp8 e4m3, K-BLOCKED: segment s holds k=[32s,32s+32) for
//              all rows: byte addr = s*131072 + row*32 + (k&31). Each segment
//              is row-contiguous -> simtile stages it with LINEAR copies.
// [1MB,+16KB): S[4096] (fp32, sum_{j!=i} exp(sim_ij))
// then       : posSum (fp32)

__device__ __forceinline__ void async_copy16(const void* gsrc, void* ldst) {
    __builtin_amdgcn_global_load_lds(
        (__attribute__((address_space(1))) void*)gsrc,
        (__attribute__((address_space(3))) void*)ldst,
        16, 0, 0);
}

// ---------- kernel 1: row-normalize fp32 -> fp8 e4m3, K-blocked store -------
// Also zero-inits S[row] and posSum.
__global__ __launch_bounds__(256)
void ntx_normalize(const float* __restrict__ z_i,
                   const float* __restrict__ z_j,
                   unsigned* __restrict__ zn8t,  // dword view of K-blocked buf
                   float* __restrict__ S,
                   float* __restrict__ posSum) {
    const int w    = threadIdx.x >> 6;               // wave 0..3
    const int lane = threadIdx.x & 63;
    const int row  = blockIdx.x * 4 + w;             // 0..4095
    const float* src = (row < B_PAIRS) ? (z_i + (size_t)row * D_DIM)
                                       : (z_j + (size_t)(row - B_PAIRS) * D_DIM);
    const float4 v = *(const float4*)(src + lane * 4);   // k = lane*4 .. +3
    float ss = v.x * v.x + v.y * v.y + v.z * v.z + v.w * v.w;
    #pragma unroll
    for (int off = 32; off > 0; off >>= 1) ss += __shfl_xor(ss, off, 64);
    const float rn = 1.0f / fmaxf(sqrtf(ss), 1e-8f);
    unsigned pk = 0;
    pk = __builtin_amdgcn_cvt_pk_fp8_f32(v.x * rn, v.y * rn, pk, false);
    pk = __builtin_amdgcn_cvt_pk_fp8_f32(v.z * rn, v.w * rn, pk, true);
    // k = lane*4 -> segment s = lane>>3, dword-in-seg = row*8 + (lane&7)
    zn8t[(size_t)(lane >> 3) * 32768 + row * 8 + (lane & 7)] = pk;
    if (lane == 0) S[row] = 0.0f;
    if (blockIdx.x == 0 && threadIdx.x == 0) *posSum = 0.0f;
}

// ---------- kernel 2: upper-triangle sim tiles, SINGLE-DRAIN K loop ---------
// Full K (256) staged at once: 64 KB LDS, ONE vmcnt-drain + barrier per block
// (rounds 6/9/10 evidence: per-block time ~ serial staging drains, not bytes).
// Fused finalize via atomic counter tested twice (R4 +8us, R11 +6us): the
// forced atomic-completion wait + single-address RMW serialization costs more
// than the saved graph node. Keep 3 kernels.
#define BM 128
#define BN 128
#define N_TILES 528            // 32 diag + 496 strictly-upper (32x32 tile grid)

__global__ __launch_bounds__(256)
void ntx_simtile(const unsigned char* __restrict__ zn8t,
                 float* __restrict__ S,
                 float* __restrict__ posSum) {
    __shared__ __align__(16) unsigned char As[8 * 128 * 32];   // 32 KB
    __shared__ __align__(16) unsigned char Bs[8 * 128 * 32];   // 32 KB

    // linear block id -> upper-triangle (by, bx), bx >= by
    int t = blockIdx.x, by = 0, rowlen = 32;
    while (t >= rowlen) { t -= rowlen; by++; rowlen--; }
    const int bx = by + t;

    const int tid  = threadIdx.x;
    const int lane = tid & 63;
    const int w    = tid >> 6;           // wave 0..3
    const int wr   = w >> 1;             // wave row strip (0..1)
    const int wc   = w & 1;              // wave col strip (0..1)
    const int quad = lane >> 4;          // 0..3
    const int l16  = lane & 15;

    const int rowA0 = by * BM;
    const int rowB0 = bx * BN;
    const bool isDiag = (by == bx);
    const bool isPos  = (rowB0 == (rowA0 ^ B_PAIRS));

    // Stage ALL 8 K-segments for A and B: 16 linear 16-B copies per thread.
    // Segment s of tile rows [r0, r0+128) is contiguous 4 KB at
    // zn8t + s*131072 + r0*32. LDS dest stays base + tid*16 (linear).
    #pragma unroll
    for (int s = 0; s < 8; s++) {
        async_copy16(zn8t + (size_t)s * 131072 + rowA0 * 32 + tid * 16,
                     As + s * 4096 + tid * 16);
        async_copy16(zn8t + (size_t)s * 131072 + rowB0 * 32 + tid * 16,
                     Bs + s * 4096 + tid * 16);
    }
    __syncthreads();   // the ONLY staging drain

    floatx4 acc[4][4];
    #pragma unroll
    for (int i = 0; i < 4; i++)
        #pragma unroll
        for (int j = 0; j < 4; j++)
            acc[i][j] = (floatx4){0.f, 0.f, 0.f, 0.f};

    #pragma unroll
    for (int s = 0; s < 8; s++) {        // K-steps, no barriers
        // frag k = s*32 + quad*8 + j; LDS row stride 32 B (4-way mild conflict)
        long afr[4], bfr[4];
        #pragma unroll
        for (int fi = 0; fi < 4; fi++) {
            const int ar = wr * 64 + fi * 16 + l16;
            afr[fi] = *(const long*)(const void*)(As + s * 4096 + ar * 32 + quad * 8);
        }
        #pragma unroll
        for (int fj = 0; fj < 4; fj++) {
            const int br = wc * 64 + fj * 16 + l16;
            bfr[fj] = *(const long*)(const void*)(Bs + s * 4096 + br * 32 + quad * 8);
        }
        #pragma unroll
        for (int fi = 0; fi < 4; fi++)
            #pragma unroll
            for (int fj = 0; fj < 4; fj++)
                acc[fi][fj] = __builtin_amdgcn_mfma_f32_16x16x32_fp8_fp8(
                    afr[fi], bfr[fj], acc[fi][fj], 0, 0, 0);
    }

    // Epilogue. C/D layout: col=l16, row=quad*4+reg.
    float cs[4] = {0.f, 0.f, 0.f, 0.f};
    float psum = 0.f;
    #pragma unroll
    for (int fi = 0; fi < 4; fi++) {
        float rs[4] = {0.f, 0.f, 0.f, 0.f};
        #pragma unroll
        for (int fj = 0; fj < 4; fj++) {
            const int rj = wc * 64 + fj * 16 + l16;
            #pragma unroll
            for (int reg = 0; reg < 4; reg++) {
                const int ri = wr * 64 + fi * 16 + quad * 4 + reg;
                const float v = acc[fi][fj][reg] * INV_T;
                const bool d = (ri == rj);
                if (isPos && d) psum += 2.0f * v;
                const float e = (isDiag && d) ? 0.f : __expf(v);
                rs[reg] += e;
                cs[fj]  += e;
            }
        }
        #pragma unroll
        for (int reg = 0; reg < 4; reg++) {
            float r = rs[reg];
            r += __shfl_xor(r, 1, 16);
            r += __shfl_xor(r, 2, 16);
            r += __shfl_xor(r, 4, 16);
            r += __shfl_xor(r, 8, 16);
            if (l16 == 0)
                atomicAdd(&S[rowA0 + wr * 64 + fi * 16 + quad * 4 + reg], r);
        }
    }
    if (!isDiag) {
        #pragma unroll
        for (int fj = 0; fj < 4; fj++) {
            float c = cs[fj];
            c += __shfl_xor(c, 16, 64);
            c += __shfl_xor(c, 32, 64);
            if (quad == 0)
                atomicAdd(&S[rowB0 + wc * 64 + fj * 16 + l16], c);
        }
    }
    if (isPos) {
        psum += __shfl_xor(psum, 1, 64);  psum += __shfl_xor(psum, 2, 64);
        psum += __shfl_xor(psum, 4, 64);  psum += __shfl_xor(psum, 8, 64);
        psum += __shfl_xor(psum, 16, 64); psum += __shfl_xor(psum, 32, 64);
        __shared__ float pred[4];
        if (lane == 0) pred[w] = psum;
        __syncthreads();
        if (tid == 0)
            atomicAdd(posSum, pred[0] + pred[1] + pred[2] + pred[3]);
    }
}

// ---------- kernel 3: loss = (sum log S_i - posSum) / N ----------
__global__ __launch_bounds__(1024)
void ntx_finalize(const float* __restrict__ S,
                  const float* __restrict__ posSum,
                  float* __restrict__ out) {
    const int tid = threadIdx.x;   // 1024 threads
    float acc = 0.f;
    #pragma unroll
    for (int c = 0; c < 4; c++)
        acc += __logf(S[tid + c * 1024]);
    #pragma unroll
    for (int off = 32; off > 0; off >>= 1) acc += __shfl_xor(acc, off, 64);
    __shared__ float red[16];
    if ((tid & 63) == 0) red[tid >> 6] = acc;
    __syncthreads();
    if (tid == 0) {
        float s = 0.f;
        #pragma unroll
        for (int k = 0; k < 16; k++) s += red[k];
        out[0] = (s - *posSum) / (float)N_ROWS;
    }
}

extern "C" void kernel_launch(void* const* d_in, const int* in_sizes, int n_in,
                              void* d_out, int out_size, void* d_ws, size_t ws_size,
                              hipStream_t stream) {
    const float* z_i = (const float*)d_in[0];
    const float* z_j = (const float*)d_in[1];
    float* out = (float*)d_out;

    unsigned char* zn8t = (unsigned char*)d_ws;
    float* S      = (float*)((char*)d_ws + (size_t)N_ROWS * D_DIM);  // 1 MB
    float* posSum = S + N_ROWS;

    ntx_normalize<<<N_ROWS / 4, 256, 0, stream>>>(z_i, z_j, (unsigned*)zn8t, S, posSum);
    ntx_simtile<<<N_TILES, 256, 0, stream>>>(zn8t, S, posSum);
    ntx_finalize<<<1, 1024, 0, stream>>>(S, posSum, out);
}